// Round 9
// baseline (200.200 us; speedup 1.0000x reference)
//
#include <hip/hip_runtime.h>
#include <hip/hip_bf16.h>

typedef __bf16 bf16x8 __attribute__((ext_vector_type(8)));
typedef float  f32x16 __attribute__((ext_vector_type(16)));

// float -> bf16 round-to-nearest-even (finite inputs)
__device__ __forceinline__ unsigned short f2bf(float f) {
    union { float f; unsigned int u; } v; v.f = f;
    unsigned int r = v.u + 0x7FFFu + ((v.u >> 16) & 1u);
    return (unsigned short)(r >> 16);
}
__device__ __forceinline__ float bf2f(unsigned short h) {
    union { unsigned int u; float f; } v; v.u = ((unsigned int)h) << 16; return v.f;
}

__device__ __forceinline__ void async16(const unsigned short* g, unsigned short* l) {
    __builtin_amdgcn_global_load_lds(
        (const __attribute__((address_space(1))) unsigned int*)g,
        (__attribute__((address_space(3))) unsigned int*)l,
        16, 0, 0);
}

// ---------------------------------------------------------------------------
// Transpose + cast + even/odd row pack: Xt[n][pi(m)] = (bf16) X[m][n]
// pi(m) = m/2 for even m, 2048 + m/2 for odd m  (even rows first)
// ---------------------------------------------------------------------------
__global__ __launch_bounds__(256) void transpose_perm(
    const float* __restrict__ X, unsigned short* __restrict__ Xt, int Mr, int Nc)
{
    __shared__ float tile[32][33];
    const int bx = blockIdx.x * 32;
    const int by = blockIdx.y * 32;
    const int tx = threadIdx.x & 31;
    const int ty = threadIdx.x >> 5;
    const int half = Mr >> 1;
#pragma unroll
    for (int j = 0; j < 4; ++j)
        tile[ty + j * 8][tx] = X[(size_t)(by + ty + j * 8) * Nc + bx + tx];
    __syncthreads();
    const int m = by + tx;
    const int pim = (m & 1) ? (half + (m >> 1)) : (m >> 1);
#pragma unroll
    for (int j = 0; j < 4; ++j)
        Xt[(size_t)(bx + ty + j * 8) * Mr + pim] = f2bf(tile[tx][ty + j * 8]);
}

// ---------------------------------------------------------------------------
// Generate packed half-transform matrix W [2048][4096]:
//   col < 2048: kk = 2*col  (even part);  col >= 2048: kk = 2*(col-2048)+1
//   W[r][col] = sin(pi*kk*(2r+1)/8192)  (doSin) else cos(...)
// ---------------------------------------------------------------------------
__global__ __launch_bounds__(256) void gen_w(
    unsigned short* __restrict__ out, int doSin)
{
    const int flat = (int)(((size_t)blockIdx.x * 256 + threadIdx.x) * 4);
    const int r  = flat >> 12;
    const int c0 = flat & 4095;
    const unsigned int step = 2u * (unsigned int)r + 1u;
    const float scale = 3.14159265358979323846f / 8192.0f;
    unsigned short o[4];
#pragma unroll
    for (int j = 0; j < 4; ++j) {
        const int c = c0 + j;
        const unsigned int kk = (c < 2048) ? (unsigned int)(2 * c)
                                           : (unsigned int)(2 * (c - 2048) + 1);
        unsigned int p = (kk * step) & 16383u;
        float ang = (float)p * scale;
        float v = doSin ? __sinf(ang) : __cosf(ang);
        o[j] = f2bf(v);
    }
    uint2 pack;
    pack.x = (unsigned int)o[0] | ((unsigned int)o[1] << 16);
    pack.y = (unsigned int)o[2] | ((unsigned int)o[3] << 16);
    *reinterpret_cast<uint2*>(out + flat) = pack;
}

// ---------------------------------------------------------------------------
// Butterfly 1: S [2][2048][4096] bf16 (S_e, S_o)  ->  T [4096][4096] bf16
//   T[u][pi(j)]      = S_e[u][j] + S_o[u][j]
//   T[4095-u][pi(j)] = S_o[u][j] - S_e[u][j]
// ---------------------------------------------------------------------------
__global__ __launch_bounds__(256) void butterfly1(
    const unsigned short* __restrict__ S, unsigned short* __restrict__ T)
{
    const int f  = (int)(((size_t)blockIdx.x * 256 + threadIdx.x) * 8);
    const int u  = f >> 12;
    const int j0 = f & 4095;
    const size_t base = (size_t)u * 4096 + j0;
    const uint4 ev = *reinterpret_cast<const uint4*>(S + base);
    const uint4 ov = *reinterpret_cast<const uint4*>(S + (size_t)2048 * 4096 + base);
    float e[8], o[8];
    e[0]=bf2f(ev.x&0xffff); e[1]=bf2f(ev.x>>16); e[2]=bf2f(ev.y&0xffff); e[3]=bf2f(ev.y>>16);
    e[4]=bf2f(ev.z&0xffff); e[5]=bf2f(ev.z>>16); e[6]=bf2f(ev.w&0xffff); e[7]=bf2f(ev.w>>16);
    o[0]=bf2f(ov.x&0xffff); o[1]=bf2f(ov.x>>16); o[2]=bf2f(ov.y&0xffff); o[3]=bf2f(ov.y>>16);
    o[4]=bf2f(ov.z&0xffff); o[5]=bf2f(ov.z>>16); o[6]=bf2f(ov.w&0xffff); o[7]=bf2f(ov.w>>16);
    float s[8], d[8];
#pragma unroll
    for (int i = 0; i < 8; ++i) { s[i] = e[i] + o[i]; d[i] = o[i] - e[i]; }
    uint2 s_ev, s_od, d_ev, d_od;
    s_ev.x = (unsigned int)f2bf(s[0]) | ((unsigned int)f2bf(s[2]) << 16);
    s_ev.y = (unsigned int)f2bf(s[4]) | ((unsigned int)f2bf(s[6]) << 16);
    s_od.x = (unsigned int)f2bf(s[1]) | ((unsigned int)f2bf(s[3]) << 16);
    s_od.y = (unsigned int)f2bf(s[5]) | ((unsigned int)f2bf(s[7]) << 16);
    d_ev.x = (unsigned int)f2bf(d[0]) | ((unsigned int)f2bf(d[2]) << 16);
    d_ev.y = (unsigned int)f2bf(d[4]) | ((unsigned int)f2bf(d[6]) << 16);
    d_od.x = (unsigned int)f2bf(d[1]) | ((unsigned int)f2bf(d[3]) << 16);
    d_od.y = (unsigned int)f2bf(d[5]) | ((unsigned int)f2bf(d[7]) << 16);
    const int jc = j0 >> 1;            // multiple of 4
    unsigned short* Tu = T + (size_t)u * 4096;
    unsigned short* Tr = T + (size_t)(4095 - u) * 4096;
    *reinterpret_cast<uint2*>(Tu + jc)         = s_ev;
    *reinterpret_cast<uint2*>(Tu + 2048 + jc)  = s_od;
    *reinterpret_cast<uint2*>(Tr + jc)         = d_ev;
    *reinterpret_cast<uint2*>(Tr + 2048 + jc)  = d_od;
}

// ---------------------------------------------------------------------------
// Butterfly 2: S2 [2][4096][2048] bf16 (E, O) -> out [4096][4096] f32
//   out[u][v]      = E[u][v] + O[u][v]
//   out[u][4095-v] = E[u][v] - O[u][v]
// ---------------------------------------------------------------------------
__global__ __launch_bounds__(256) void butterfly2(
    const unsigned short* __restrict__ S2, float* __restrict__ out)
{
    const int f  = (int)(((size_t)blockIdx.x * 256 + threadIdx.x) * 8);
    const int u  = f >> 11;
    const int v0 = f & 2047;
    const size_t base = (size_t)u * 2048 + v0;
    const uint4 ev = *reinterpret_cast<const uint4*>(S2 + base);
    const uint4 ov = *reinterpret_cast<const uint4*>(S2 + (size_t)4096 * 2048 + base);
    float e[8], o[8];
    e[0]=bf2f(ev.x&0xffff); e[1]=bf2f(ev.x>>16); e[2]=bf2f(ev.y&0xffff); e[3]=bf2f(ev.y>>16);
    e[4]=bf2f(ev.z&0xffff); e[5]=bf2f(ev.z>>16); e[6]=bf2f(ev.w&0xffff); e[7]=bf2f(ev.w>>16);
    o[0]=bf2f(ov.x&0xffff); o[1]=bf2f(ov.x>>16); o[2]=bf2f(ov.y&0xffff); o[3]=bf2f(ov.y>>16);
    o[4]=bf2f(ov.z&0xffff); o[5]=bf2f(ov.z>>16); o[6]=bf2f(ov.w&0xffff); o[7]=bf2f(ov.w>>16);
    float* row = out + (size_t)u * 4096;
    float4 a0 = { e[0]+o[0], e[1]+o[1], e[2]+o[2], e[3]+o[3] };
    float4 a1 = { e[4]+o[4], e[5]+o[5], e[6]+o[6], e[7]+o[7] };
    *reinterpret_cast<float4*>(row + v0)     = a0;
    *reinterpret_cast<float4*>(row + v0 + 4) = a1;
    float4 r0 = { e[7]-o[7], e[6]-o[6], e[5]-o[5], e[4]-o[4] };
    float4 r1 = { e[3]-o[3], e[2]-o[2], e[1]-o[1], e[0]-o[0] };
    *reinterpret_cast<float4*>(row + 4088 - v0) = r0;
    *reinterpret_cast<float4*>(row + 4092 - v0) = r1;
}

// ---------------------------------------------------------------------------
// 256x256 BT-layout bf16 GEMM (barrier-minimal tile), 32x32x16 MFMA, z-split:
//   Cz[i][j] = sum_k Pz[i][k] * Qz[j][k]
// BK=64, 8 waves (2Mx4N), per-wave 128x64 C as 4x2 32x32 frags.
// A/B frag: row/col = lane&31, k = (lane>>5)*8 + e (8 contiguous bf16, b128).
// C/D frag (measured m74/m101): col=lane&31, row=(reg&3)+8*(reg>>2)+4*(lane>>5).
// ---------------------------------------------------------------------------
__device__ __forceinline__ void store_out(float* C, size_t idx, float v) { C[idx] = v; }
__device__ __forceinline__ void store_out(unsigned short* C, size_t idx, float v) { C[idx] = f2bf(v); }

#define BARRIER __builtin_amdgcn_s_barrier()
#define PRIO1 __builtin_amdgcn_s_setprio(1)
#define PRIO0 __builtin_amdgcn_s_setprio(0)

#define STG_A(buf, h, L, kt) async16(pA + (size_t)((h) * 128 + (L) * 64) * ldp + (size_t)(kt) * 64, \
                                     ldsA + ((buf) << 14) + ((h) << 13) + ((L) << 12) + ldst)
#define STG_B(buf, h, L, kt) async16(pB + (size_t)((h) * 128 + (L) * 64) * ldq + (size_t)(kt) * 64, \
                                     ldsB + ((buf) << 14) + ((h) << 13) + ((L) << 12) + ldst)

// swizzled 16B-slot offset for kstep ks (ushort index)
#define SL(ks) ((((ks) * 2 + lhi) ^ sxr) << 3)

// load A fragments for m-pair g (frags 2g, 2g+1): 8 x ds_read_b128
#define LDA(buf, g) do { _Pragma("unroll") for (int mm = 0; mm < 2; ++mm) \
    _Pragma("unroll") for (int ks = 0; ks < 4; ++ks) \
    af[mm][ks] = *(const bf16x8*)&ldsA[((buf) << 14) + sAb + (g) * 4096 + mm * 2048 + SL(ks)]; } while (0)

// load B fragment nf: 4 x ds_read_b128
#define LDB(buf, nf) do { _Pragma("unroll") for (int ks = 0; ks < 4; ++ks) \
    bfr[nf][ks] = *(const bf16x8*)&ldsB[((buf) << 14) + sBb + (nf) * 2048 + SL(ks)]; } while (0)

// one C-quadrant (m-pair g x n-frag nf) over K=64: 8 MFMA
#define MFMA_Q(g, nf) do { _Pragma("unroll") for (int ks = 0; ks < 4; ++ks) \
    _Pragma("unroll") for (int mm = 0; mm < 2; ++mm) \
    acc[(g) * 2 + mm][nf] = __builtin_amdgcn_mfma_f32_32x32x16_bf16( \
        af[mm][ks], bfr[nf][ks], acc[(g) * 2 + mm][nf], 0, 0, 0); } while (0)

#define TILE(buf, nbuf, kt, doSA, doSB, vmN) do { \
    LDA(buf, 0); LDB(buf, 0); \
    if (doSA) { STG_A(nbuf, 0, 0, (kt) + 1); STG_A(nbuf, 0, 1, (kt) + 1); } \
    PRIO1; MFMA_Q(0, 0); PRIO0; \
    LDB(buf, 1); \
    if (doSA) { STG_A(nbuf, 1, 0, (kt) + 1); STG_A(nbuf, 1, 1, (kt) + 1); } \
    PRIO1; MFMA_Q(0, 1); PRIO0; \
    asm volatile("s_waitcnt lgkmcnt(0)" ::: "memory"); \
    BARRIER; \
    LDA(buf, 1); \
    if (doSB) { STG_B(buf, 0, 0, (kt) + 2); STG_B(buf, 0, 1, (kt) + 2); } \
    PRIO1; MFMA_Q(1, 0); PRIO0; \
    if (doSB) { STG_B(buf, 1, 0, (kt) + 2); STG_B(buf, 1, 1, (kt) + 2); } \
    PRIO1; MFMA_Q(1, 1); PRIO0; \
    asm volatile("s_waitcnt vmcnt(" #vmN ")" ::: "memory"); \
    BARRIER; } while (0)

template <typename OutT>
__global__ __launch_bounds__(512, 2) void gemm_bt8(
    const unsigned short* __restrict__ P,
    const unsigned short* __restrict__ Q,
    OutT* __restrict__ C,
    int nbx, int K, int ldp, int ldq, int ldc,
    size_t poff, size_t qoff, size_t coff)
{
    __shared__ __align__(16) unsigned short ldsA[2 * 256 * 64];
    __shared__ __align__(16) unsigned short ldsB[2 * 256 * 64];

    const int tid  = threadIdx.x;
    const int lane = tid & 63;
    const int w    = tid >> 6;
    const int wm   = w >> 2;
    const int wn   = w & 3;

    // XCD-bijective swizzle over 256 blocks; z = which half-GEMM
    const int bid = blockIdx.x;
    const int wg  = (bid & 7) * (gridDim.x >> 3) + (bid >> 3);
    const int z   = wg >> 7;
    const int t   = wg & 127;
    const int brow = (t / nbx) << 8;
    const int bcol = (t % nbx) << 8;

    const unsigned short* Pz = P + (size_t)z * poff;
    const unsigned short* Qz = Q + (size_t)z * qoff;
    OutT* Cz = C + (size_t)z * coff;

    const int srow = tid >> 3;
    const int slot = tid & 7;
    const int sxor = ((slot ^ (srow & 7)) << 3);
    const unsigned short* pA = Pz + (size_t)(brow + srow) * ldp + sxor;
    const unsigned short* pB = Qz + (size_t)(bcol + srow) * ldq + sxor;
    const int ldst = w << 9;

    // fragment-read constants (32x32x16): row-in-unit = mm*32 + lane31
    const int lane31 = lane & 31, lhi = lane >> 5, sxr = lane31 & 7;
    const int sAb = (wm * 2) * 4096 + lane31 * 64;   // + g*4096 + mm*2048 + SL(ks)
    const int sBb = wn * 4096 + lane31 * 64;         // + nf*2048 + SL(ks)

    bf16x8 af[2][4], bfr[2][4];
    f32x16 acc[4][2] = {};

    const int nt = K >> 6;

    STG_A(0, 0, 0, 0); STG_A(0, 0, 1, 0); STG_A(0, 1, 0, 0); STG_A(0, 1, 1, 0);
    STG_B(0, 0, 0, 0); STG_B(0, 0, 1, 0); STG_B(0, 1, 0, 0); STG_B(0, 1, 1, 0);
    STG_B(1, 0, 0, 1); STG_B(1, 0, 1, 1); STG_B(1, 1, 0, 1); STG_B(1, 1, 1, 1);
    asm volatile("s_waitcnt vmcnt(4)" ::: "memory");
    BARRIER;

    for (int i = 0; i < (nt >> 1) - 1; ++i) {
        const int t0 = 2 * i;
        TILE(0, 1, t0,     1, 1, 4);
        TILE(1, 0, t0 + 1, 1, 1, 4);
    }
    TILE(0, 1, nt - 2, 1, 0, 0);
    TILE(1, 0, nt - 1, 0, 0, 0);

    // epilogue: col=lane31 (+nf*32), row=(reg&3)+8*(reg>>2)+4*lhi (+mf*32)
#pragma unroll
    for (int mf = 0; mf < 4; ++mf) {
        const int rbase = brow + wm * 128 + mf * 32 + lhi * 4;
#pragma unroll
        for (int nf = 0; nf < 2; ++nf) {
            const int col = bcol + wn * 64 + nf * 32 + lane31;
#pragma unroll
            for (int reg = 0; reg < 16; ++reg) {
                const int row = rbase + (reg & 3) + 8 * (reg >> 2);
                store_out(Cz, (size_t)row * ldc + col, acc[mf][nf][reg]);
            }
        }
    }
}

// ---------------------------------------------------------------------------
// launch. Even/odd split (2x FLOP reduction per stage):
//   stage1: S_e = A_e (.) Xt_even, S_o = A_o (.) Xt_odd   (one dispatch, z-split)
//           T[u] = S_e+S_o ; T[4095-u] = S_o-S_e          (butterfly1, pi-packed)
//   stage2: E = T_even (.) B_e, O = T_odd (.) B_o         (one dispatch, z-split)
//           out[u][v] = E+O ; out[u][4095-v] = E-O        (butterfly2, f32)
// ws: R0 Xt_perm->T_perm (32MB) | R1 W1->W2 (16MB) | R2 S1->S2 (32MB) = 80MB
// ---------------------------------------------------------------------------
extern "C" void kernel_launch(void* const* d_in, const int* in_sizes, int n_in,
                              void* d_out, int out_size, void* d_ws, size_t ws_size,
                              hipStream_t stream) {
    const float* X = (const float*)d_in[0];
    const int Mr = in_sizes[1] / 2;   // 4096
    const int Nc = in_sizes[2] / 2;   // 4096

    unsigned short* R0 = (unsigned short*)d_ws;                    // [4096][4096] bf16
    unsigned short* R1 = R0 + (size_t)Mr * Nc;                     // [2048][4096] bf16
    unsigned short* R2 = R1 + (size_t)(Mr / 2) * Nc;               // [2][2048][4096] bf16

    transpose_perm<<<dim3(Nc / 32, Mr / 32), 256, 0, stream>>>(X, R0, Mr, Nc);
    gen_w<<<(2048 * 4096 / 4) / 256, 256, 0, stream>>>(R1, 1);
    gemm_bt8<unsigned short><<<256, 512, 0, stream>>>(
        R1, R0, R2, /*nbx=*/16, /*K=*/2048, /*ldp=*/4096, /*ldq=*/4096, /*ldc=*/4096,
        /*poff=*/2048, /*qoff=*/2048, /*coff=*/(size_t)2048 * 4096);
    butterfly1<<<(2048 * 4096 / 8) / 256, 256, 0, stream>>>(R2, R0);
    gen_w<<<(2048 * 4096 / 4) / 256, 256, 0, stream>>>(R1, 0);
    gemm_bt8<unsigned short><<<256, 512, 0, stream>>>(
        R0, R1, R2, /*nbx=*/8, /*K=*/2048, /*ldp=*/4096, /*ldq=*/4096, /*ldc=*/2048,
        /*poff=*/2048, /*qoff=*/2048, /*coff=*/(size_t)4096 * 2048);
    butterfly2<<<(4096 * 2048 / 8) / 256, 256, 0, stream>>>(R2, (float*)d_out);
}

// Round 10
// 183.621 us; speedup vs baseline: 1.0903x; 1.0903x over previous
//
#include <hip/hip_runtime.h>
#include <hip/hip_bf16.h>

typedef __bf16 bf16x8 __attribute__((ext_vector_type(8)));
typedef float  f32x4  __attribute__((ext_vector_type(4)));

// float -> bf16 round-to-nearest-even (finite inputs)
__device__ __forceinline__ unsigned short f2bf(float f) {
    union { float f; unsigned int u; } v; v.f = f;
    unsigned int r = v.u + 0x7FFFu + ((v.u >> 16) & 1u);
    return (unsigned short)(r >> 16);
}
__device__ __forceinline__ float bf2f(unsigned short h) {
    union { unsigned int u; float f; } v; v.u = ((unsigned int)h) << 16; return v.f;
}

__device__ __forceinline__ void async16(const unsigned short* g, unsigned short* l) {
    __builtin_amdgcn_global_load_lds(
        (const __attribute__((address_space(1))) unsigned int*)g,
        (__attribute__((address_space(3))) unsigned int*)l,
        16, 0, 0);
}

// ---------------------------------------------------------------------------
// Transpose + cast + even/odd row pack: Xt[n][pi(m)] = (bf16) X[m][n]
// pi(m) = m/2 (even m) | 2048 + m/2 (odd m).  64x64 tile, float4 reads,
// ushort4 writes: per n-row, halves are 64B-contiguous runs.
// ---------------------------------------------------------------------------
__global__ __launch_bounds__(256) void transpose_perm(
    const float* __restrict__ X, unsigned short* __restrict__ Xt, int Mr, int Nc)
{
    __shared__ float tile[64][65];
    const int bx = blockIdx.x * 64;   // n base
    const int by = blockIdx.y * 64;   // m base
    const int tid = threadIdx.x;
    const int halfM = Mr >> 1;

    // read: 4 passes x (16 rows x 16 float4)
    const int c4 = (tid & 15) * 4;
    const int r  = tid >> 4;          // 0..15
#pragma unroll
    for (int p = 0; p < 4; ++p) {
        const float4 v = *reinterpret_cast<const float4*>(
            &X[(size_t)(by + r + 16 * p) * Nc + bx + c4]);
        tile[r + 16 * p][c4 + 0] = v.x;
        tile[r + 16 * p][c4 + 1] = v.y;
        tile[r + 16 * p][c4 + 2] = v.z;
        tile[r + 16 * p][c4 + 3] = v.w;
    }
    __syncthreads();

    // write: lane covers (n-row = tid>>4 per pass, h = (tid>>3)&1, q = tid&7)
    // m = by + 8q + 2e + h, e=0..3  ->  pi col = h*halfM + by/2 + 4q + e
    const int q  = tid & 7;
    const int h  = (tid >> 3) & 1;
    const int n0 = tid >> 4;          // 0..15
#pragma unroll
    for (int p = 0; p < 4; ++p) {
        const int n = n0 + 16 * p;
        ushort4 o;
        o.x = f2bf(tile[8 * q + 0 + h][n]);
        o.y = f2bf(tile[8 * q + 2 + h][n]);
        o.z = f2bf(tile[8 * q + 4 + h][n]);
        o.w = f2bf(tile[8 * q + 6 + h][n]);
        *reinterpret_cast<ushort4*>(
            Xt + (size_t)(bx + n) * Mr + h * halfM + (by >> 1) + 4 * q) = o;
    }
}

// ---------------------------------------------------------------------------
// Generate packed half-transform matrix W [2048][4096]:
//   col < 2048: kk = 2*col  (even part);  col >= 2048: kk = 2*(col-2048)+1
//   W[r][col] = sin(pi*kk*(2r+1)/8192)  (doSin) else cos(...)
// ---------------------------------------------------------------------------
__global__ __launch_bounds__(256) void gen_w(
    unsigned short* __restrict__ out, int doSin)
{
    const int flat = (int)(((size_t)blockIdx.x * 256 + threadIdx.x) * 4);
    const int r  = flat >> 12;
    const int c0 = flat & 4095;
    const unsigned int step = 2u * (unsigned int)r + 1u;
    const float scale = 3.14159265358979323846f / 8192.0f;
    unsigned short o[4];
#pragma unroll
    for (int j = 0; j < 4; ++j) {
        const int c = c0 + j;
        const unsigned int kk = (c < 2048) ? (unsigned int)(2 * c)
                                           : (unsigned int)(2 * (c - 2048) + 1);
        unsigned int p = (kk * step) & 16383u;
        float ang = (float)p * scale;
        float v = doSin ? __sinf(ang) : __cosf(ang);
        o[j] = f2bf(v);
    }
    uint2 pack;
    pack.x = (unsigned int)o[0] | ((unsigned int)o[1] << 16);
    pack.y = (unsigned int)o[2] | ((unsigned int)o[3] << 16);
    *reinterpret_cast<uint2*>(out + flat) = pack;
}

// ---------------------------------------------------------------------------
// Butterfly 1: S [2][2048][4096] bf16 (S_e, S_o)  ->  T [4096][4096] bf16
//   T[u][pi(j)]      = S_e[u][j] + S_o[u][j]
//   T[4095-u][pi(j)] = S_o[u][j] - S_e[u][j]
// ---------------------------------------------------------------------------
__global__ __launch_bounds__(256) void butterfly1(
    const unsigned short* __restrict__ S, unsigned short* __restrict__ T)
{
    const int f  = (int)(((size_t)blockIdx.x * 256 + threadIdx.x) * 8);
    const int u  = f >> 12;
    const int j0 = f & 4095;
    const size_t base = (size_t)u * 4096 + j0;
    const uint4 ev = *reinterpret_cast<const uint4*>(S + base);
    const uint4 ov = *reinterpret_cast<const uint4*>(S + (size_t)2048 * 4096 + base);
    float e[8], o[8];
    e[0]=bf2f(ev.x&0xffff); e[1]=bf2f(ev.x>>16); e[2]=bf2f(ev.y&0xffff); e[3]=bf2f(ev.y>>16);
    e[4]=bf2f(ev.z&0xffff); e[5]=bf2f(ev.z>>16); e[6]=bf2f(ev.w&0xffff); e[7]=bf2f(ev.w>>16);
    o[0]=bf2f(ov.x&0xffff); o[1]=bf2f(ov.x>>16); o[2]=bf2f(ov.y&0xffff); o[3]=bf2f(ov.y>>16);
    o[4]=bf2f(ov.z&0xffff); o[5]=bf2f(ov.z>>16); o[6]=bf2f(ov.w&0xffff); o[7]=bf2f(ov.w>>16);
    float s[8], d[8];
#pragma unroll
    for (int i = 0; i < 8; ++i) { s[i] = e[i] + o[i]; d[i] = o[i] - e[i]; }
    uint2 s_ev, s_od, d_ev, d_od;
    s_ev.x = (unsigned int)f2bf(s[0]) | ((unsigned int)f2bf(s[2]) << 16);
    s_ev.y = (unsigned int)f2bf(s[4]) | ((unsigned int)f2bf(s[6]) << 16);
    s_od.x = (unsigned int)f2bf(s[1]) | ((unsigned int)f2bf(s[3]) << 16);
    s_od.y = (unsigned int)f2bf(s[5]) | ((unsigned int)f2bf(s[7]) << 16);
    d_ev.x = (unsigned int)f2bf(d[0]) | ((unsigned int)f2bf(d[2]) << 16);
    d_ev.y = (unsigned int)f2bf(d[4]) | ((unsigned int)f2bf(d[6]) << 16);
    d_od.x = (unsigned int)f2bf(d[1]) | ((unsigned int)f2bf(d[3]) << 16);
    d_od.y = (unsigned int)f2bf(d[5]) | ((unsigned int)f2bf(d[7]) << 16);
    const int jc = j0 >> 1;            // multiple of 4
    unsigned short* Tu = T + (size_t)u * 4096;
    unsigned short* Tr = T + (size_t)(4095 - u) * 4096;
    *reinterpret_cast<uint2*>(Tu + jc)         = s_ev;
    *reinterpret_cast<uint2*>(Tu + 2048 + jc)  = s_od;
    *reinterpret_cast<uint2*>(Tr + jc)         = d_ev;
    *reinterpret_cast<uint2*>(Tr + 2048 + jc)  = d_od;
}

// ---------------------------------------------------------------------------
// Butterfly 2: S2 [2][4096][2048] bf16 (E, O) -> out [4096][4096] f32
//   out[u][v]      = E[u][v] + O[u][v]
//   out[u][4095-v] = E[u][v] - O[u][v]
// ---------------------------------------------------------------------------
__global__ __launch_bounds__(256) void butterfly2(
    const unsigned short* __restrict__ S2, float* __restrict__ out)
{
    const int f  = (int)(((size_t)blockIdx.x * 256 + threadIdx.x) * 8);
    const int u  = f >> 11;
    const int v0 = f & 2047;
    const size_t base = (size_t)u * 2048 + v0;
    const uint4 ev = *reinterpret_cast<const uint4*>(S2 + base);
    const uint4 ov = *reinterpret_cast<const uint4*>(S2 + (size_t)4096 * 2048 + base);
    float e[8], o[8];
    e[0]=bf2f(ev.x&0xffff); e[1]=bf2f(ev.x>>16); e[2]=bf2f(ev.y&0xffff); e[3]=bf2f(ev.y>>16);
    e[4]=bf2f(ev.z&0xffff); e[5]=bf2f(ev.z>>16); e[6]=bf2f(ev.w&0xffff); e[7]=bf2f(ev.w>>16);
    o[0]=bf2f(ov.x&0xffff); o[1]=bf2f(ov.x>>16); o[2]=bf2f(ov.y&0xffff); o[3]=bf2f(ov.y>>16);
    o[4]=bf2f(ov.z&0xffff); o[5]=bf2f(ov.z>>16); o[6]=bf2f(ov.w&0xffff); o[7]=bf2f(ov.w>>16);
    float* row = out + (size_t)u * 4096;
    float4 a0 = { e[0]+o[0], e[1]+o[1], e[2]+o[2], e[3]+o[3] };
    float4 a1 = { e[4]+o[4], e[5]+o[5], e[6]+o[6], e[7]+o[7] };
    *reinterpret_cast<float4*>(row + v0)     = a0;
    *reinterpret_cast<float4*>(row + v0 + 4) = a1;
    float4 r0 = { e[7]-o[7], e[6]-o[6], e[5]-o[5], e[4]-o[4] };
    float4 r1 = { e[3]-o[3], e[2]-o[2], e[1]-o[1], e[0]-o[0] };
    *reinterpret_cast<float4*>(row + 4088 - v0) = r0;
    *reinterpret_cast<float4*>(row + 4092 - v0) = r1;
}

// ---------------------------------------------------------------------------
// 256x256 BT-layout bf16 GEMM (barrier-minimal tile), 16x16x32 MFMA, z-split:
//   Cz[i][j] = sum_k Pz[i][k] * Qz[j][k]
// BK=64, 8 waves (2Mx4N), per-wave 128x64 C. Proven config (round 8).
// ---------------------------------------------------------------------------
__device__ __forceinline__ void store_out(float* C, size_t idx, float v) { C[idx] = v; }
__device__ __forceinline__ void store_out(unsigned short* C, size_t idx, float v) { C[idx] = f2bf(v); }

#define BARRIER __builtin_amdgcn_s_barrier()
#define PRIO1 __builtin_amdgcn_s_setprio(1)
#define PRIO0 __builtin_amdgcn_s_setprio(0)

#define STG_A(buf, h, L, kt) async16(pA + (size_t)((h) * 128 + (L) * 64) * ldp + (size_t)(kt) * 64, \
                                     ldsA + ((buf) << 14) + ((h) << 13) + ((L) << 12) + ldst)
#define STG_B(buf, h, L, kt) async16(pB + (size_t)((h) * 128 + (L) * 64) * ldq + (size_t)(kt) * 64, \
                                     ldsB + ((buf) << 14) + ((h) << 13) + ((L) << 12) + ldst)

#define LDA(buf, g) do { _Pragma("unroll") for (int mm = 0; mm < 4; ++mm) { \
    af[mm][0] = *(const bf16x8*)&ldsA[((buf) << 14) + aRow + ((g) * 4 + mm) * 1024 + sl0]; \
    af[mm][1] = *(const bf16x8*)&ldsA[((buf) << 14) + aRow + ((g) * 4 + mm) * 1024 + sl1]; } } while (0)

#define LDB(buf, p) do { _Pragma("unroll") for (int nn = 0; nn < 2; ++nn) { \
    bfr[(p) * 2 + nn][0] = *(const bf16x8*)&ldsB[((buf) << 14) + bRow + (((p) * 2 + nn)) * 1024 + sl0]; \
    bfr[(p) * 2 + nn][1] = *(const bf16x8*)&ldsB[((buf) << 14) + bRow + (((p) * 2 + nn)) * 1024 + sl1]; } } while (0)

#define MFMA_Q(g, p) do { _Pragma("unroll") for (int mm = 0; mm < 4; ++mm) \
    _Pragma("unroll") for (int nn = 0; nn < 2; ++nn) { \
    acc[(g) * 4 + mm][(p) * 2 + nn] = __builtin_amdgcn_mfma_f32_16x16x32_bf16( \
        af[mm][0], bfr[(p) * 2 + nn][0], acc[(g) * 4 + mm][(p) * 2 + nn], 0, 0, 0); \
    acc[(g) * 4 + mm][(p) * 2 + nn] = __builtin_amdgcn_mfma_f32_16x16x32_bf16( \
        af[mm][1], bfr[(p) * 2 + nn][1], acc[(g) * 4 + mm][(p) * 2 + nn], 0, 0, 0); } } while (0)

#define TILE(buf, nbuf, kt, doSA, doSB, vmN) do { \
    LDA(buf, 0); LDB(buf, 0); \
    if (doSA) { STG_A(nbuf, 0, 0, (kt) + 1); STG_A(nbuf, 0, 1, (kt) + 1); } \
    PRIO1; MFMA_Q(0, 0); PRIO0; \
    LDB(buf, 1); \
    if (doSA) { STG_A(nbuf, 1, 0, (kt) + 1); STG_A(nbuf, 1, 1, (kt) + 1); } \
    PRIO1; MFMA_Q(0, 1); PRIO0; \
    asm volatile("s_waitcnt lgkmcnt(0)" ::: "memory"); \
    BARRIER; \
    LDA(buf, 1); \
    if (doSB) { STG_B(buf, 0, 0, (kt) + 2); STG_B(buf, 0, 1, (kt) + 2); } \
    PRIO1; MFMA_Q(1, 0); PRIO0; \
    if (doSB) { STG_B(buf, 1, 0, (kt) + 2); STG_B(buf, 1, 1, (kt) + 2); } \
    PRIO1; MFMA_Q(1, 1); PRIO0; \
    asm volatile("s_waitcnt vmcnt(" #vmN ")" ::: "memory"); \
    BARRIER; } while (0)

template <typename OutT>
__global__ __launch_bounds__(512, 2) void gemm_bt8(
    const unsigned short* __restrict__ P,
    const unsigned short* __restrict__ Q,
    OutT* __restrict__ C,
    int nbx, int K, int ldp, int ldq, int ldc,
    size_t poff, size_t qoff, size_t coff)
{
    __shared__ __align__(16) unsigned short ldsA[2 * 256 * 64];
    __shared__ __align__(16) unsigned short ldsB[2 * 256 * 64];

    const int tid  = threadIdx.x;
    const int lane = tid & 63;
    const int w    = tid >> 6;
    const int wm   = w >> 2;
    const int wn   = w & 3;

    // XCD-bijective swizzle over 256 blocks; z = which half-GEMM
    const int bid = blockIdx.x;
    const int wg  = (bid & 7) * (gridDim.x >> 3) + (bid >> 3);
    const int z   = wg >> 7;
    const int t   = wg & 127;
    const int brow = (t / nbx) << 8;
    const int bcol = (t % nbx) << 8;

    const unsigned short* Pz = P + (size_t)z * poff;
    const unsigned short* Qz = Q + (size_t)z * qoff;
    OutT* Cz = C + (size_t)z * coff;

    const int srow = tid >> 3;
    const int slot = tid & 7;
    const int sxor = ((slot ^ (srow & 7)) << 3);
    const unsigned short* pA = Pz + (size_t)(brow + srow) * ldp + sxor;
    const unsigned short* pB = Qz + (size_t)(bcol + srow) * ldq + sxor;
    const int ldst = w << 9;

    const int lr = lane & 15, lk = lane >> 4, sx = lr & 7;
    const int sl0 = ((lk) ^ sx) << 3;
    const int sl1 = ((4 + lk) ^ sx) << 3;
    const int aRow = (wm * 128 + lr) * 64;
    const int bRow = (wn * 64 + lr) * 64;

    bf16x8 af[4][2], bfr[4][2];
    f32x4 acc[8][4] = {};

    const int nt = K >> 6;   // 32

    STG_A(0, 0, 0, 0); STG_A(0, 0, 1, 0); STG_A(0, 1, 0, 0); STG_A(0, 1, 1, 0);
    STG_B(0, 0, 0, 0); STG_B(0, 0, 1, 0); STG_B(0, 1, 0, 0); STG_B(0, 1, 1, 0);
    STG_B(1, 0, 0, 1); STG_B(1, 0, 1, 1); STG_B(1, 1, 0, 1); STG_B(1, 1, 1, 1);
    asm volatile("s_waitcnt vmcnt(4)" ::: "memory");
    BARRIER;

    for (int i = 0; i < (nt >> 1) - 1; ++i) {
        const int t0 = 2 * i;
        TILE(0, 1, t0,     1, 1, 4);
        TILE(1, 0, t0 + 1, 1, 1, 4);
    }
    TILE(0, 1, nt - 2, 1, 0, 0);
    TILE(1, 0, nt - 1, 0, 0, 0);

    const int r0 = brow + wm * 128 + (lane >> 4) * 4;
    const int c0 = bcol + wn * 64 + (lane & 15);
#pragma unroll
    for (int m = 0; m < 8; ++m)
#pragma unroll
        for (int n = 0; n < 4; ++n)
#pragma unroll
            for (int r = 0; r < 4; ++r)
                store_out(Cz, (size_t)(r0 + m * 16 + r) * ldc + (c0 + n * 16), acc[m][n][r]);
}

// ---------------------------------------------------------------------------
// launch. Even/odd split (2x FLOP reduction per stage):
//   stage1: S_e = A_e (.) Xt_even, S_o = A_o (.) Xt_odd   (one dispatch, z-split)
//           T[u] = S_e+S_o ; T[4095-u] = S_o-S_e          (butterfly1, pi-packed)
//   stage2: E = T_even (.) B_e, O = T_odd (.) B_o         (one dispatch, z-split)
//           out[u][v] = E+O ; out[u][4095-v] = E-O        (butterfly2, f32)
// ws: R0 Xt_perm->T_perm (32MB) | R1 W1->W2 (16MB) | R2 S1->S2 (32MB) = 80MB
// ---------------------------------------------------------------------------
extern "C" void kernel_launch(void* const* d_in, const int* in_sizes, int n_in,
                              void* d_out, int out_size, void* d_ws, size_t ws_size,
                              hipStream_t stream) {
    const float* X = (const float*)d_in[0];
    const int Mr = in_sizes[1] / 2;   // 4096
    const int Nc = in_sizes[2] / 2;   // 4096

    unsigned short* R0 = (unsigned short*)d_ws;                    // [4096][4096] bf16
    unsigned short* R1 = R0 + (size_t)Mr * Nc;                     // [2048][4096] bf16
    unsigned short* R2 = R1 + (size_t)(Mr / 2) * Nc;               // [2][2048][4096] bf16

    transpose_perm<<<dim3(Nc / 64, Mr / 64), 256, 0, stream>>>(X, R0, Mr, Nc);
    gen_w<<<(2048 * 4096 / 4) / 256, 256, 0, stream>>>(R1, 1);
    gemm_bt8<unsigned short><<<256, 512, 0, stream>>>(
        R1, R0, R2, /*nbx=*/16, /*K=*/2048, /*ldp=*/4096, /*ldq=*/4096, /*ldc=*/4096,
        /*poff=*/2048, /*qoff=*/2048, /*coff=*/(size_t)2048 * 4096);
    butterfly1<<<(2048 * 4096 / 8) / 256, 256, 0, stream>>>(R2, R0);
    gen_w<<<(2048 * 4096 / 4) / 256, 256, 0, stream>>>(R1, 0);
    gemm_bt8<unsigned short><<<256, 512, 0, stream>>>(
        R0, R1, R2, /*nbx=*/8, /*K=*/2048, /*ldp=*/4096, /*ldq=*/4096, /*ldc=*/2048,
        /*poff=*/2048, /*qoff=*/2048, /*coff=*/(size_t)4096 * 2048);
    butterfly2<<<(4096 * 2048 / 8) / 256, 256, 0, stream>>>(R2, (float*)d_out);
}

// Round 11
// 168.293 us; speedup vs baseline: 1.1896x; 1.0911x over previous
//
#include <hip/hip_runtime.h>
#include <hip/hip_bf16.h>

typedef __bf16 bf16x8 __attribute__((ext_vector_type(8)));
typedef float  f32x4  __attribute__((ext_vector_type(4)));

// float -> bf16 round-to-nearest-even (finite inputs)
__device__ __forceinline__ unsigned short f2bf(float f) {
    union { float f; unsigned int u; } v; v.f = f;
    unsigned int r = v.u + 0x7FFFu + ((v.u >> 16) & 1u);
    return (unsigned short)(r >> 16);
}

__device__ __forceinline__ void async16(const unsigned short* g, unsigned short* l) {
    __builtin_amdgcn_global_load_lds(
        (const __attribute__((address_space(1))) unsigned int*)g,
        (__attribute__((address_space(3))) unsigned int*)l,
        16, 0, 0);
}

// ---------------------------------------------------------------------------
// Transpose + cast + even/odd row pack: Xt[n][pi(m)] = (bf16) X[m][n]
// ---------------------------------------------------------------------------
__global__ __launch_bounds__(256) void transpose_perm(
    const float* __restrict__ X, unsigned short* __restrict__ Xt, int Mr, int Nc)
{
    __shared__ float tile[64][65];
    const int bx = blockIdx.x * 64;   // n base
    const int by = blockIdx.y * 64;   // m base
    const int tid = threadIdx.x;
    const int halfM = Mr >> 1;

    const int c4 = (tid & 15) * 4;
    const int r  = tid >> 4;
#pragma unroll
    for (int p = 0; p < 4; ++p) {
        const float4 v = *reinterpret_cast<const float4*>(
            &X[(size_t)(by + r + 16 * p) * Nc + bx + c4]);
        tile[r + 16 * p][c4 + 0] = v.x;
        tile[r + 16 * p][c4 + 1] = v.y;
        tile[r + 16 * p][c4 + 2] = v.z;
        tile[r + 16 * p][c4 + 3] = v.w;
    }
    __syncthreads();

    const int q  = tid & 7;
    const int h  = (tid >> 3) & 1;
    const int n0 = tid >> 4;
#pragma unroll
    for (int p = 0; p < 4; ++p) {
        const int n = n0 + 16 * p;
        ushort4 o;
        o.x = f2bf(tile[8 * q + 0 + h][n]);
        o.y = f2bf(tile[8 * q + 2 + h][n]);
        o.z = f2bf(tile[8 * q + 4 + h][n]);
        o.w = f2bf(tile[8 * q + 6 + h][n]);
        *reinterpret_cast<ushort4*>(
            Xt + (size_t)(bx + n) * Mr + h * halfM + (by >> 1) + 4 * q) = o;
    }
}

// ---------------------------------------------------------------------------
// Generate packed half-transform matrix W [2048][4096]:
//   col < 2048: kk = 2*col (even);  col >= 2048: kk = 2*(col-2048)+1 (odd)
//   W[r][col] = sin(pi*kk*(2r+1)/8192) (doSin) else cos(...)
// ---------------------------------------------------------------------------
__global__ __launch_bounds__(256) void gen_w(
    unsigned short* __restrict__ out, int doSin)
{
    const int flat = (int)(((size_t)blockIdx.x * 256 + threadIdx.x) * 4);
    const int r  = flat >> 12;
    const int c0 = flat & 4095;
    const unsigned int step = 2u * (unsigned int)r + 1u;
    const float scale = 3.14159265358979323846f / 8192.0f;
    unsigned short o[4];
#pragma unroll
    for (int j = 0; j < 4; ++j) {
        const int c = c0 + j;
        const unsigned int kk = (c < 2048) ? (unsigned int)(2 * c)
                                           : (unsigned int)(2 * (c - 2048) + 1);
        unsigned int p = (kk * step) & 16383u;
        float ang = (float)p * scale;
        float v = doSin ? __sinf(ang) : __cosf(ang);
        o[j] = f2bf(v);
    }
    uint2 pack;
    pack.x = (unsigned int)o[0] | ((unsigned int)o[1] << 16);
    pack.y = (unsigned int)o[2] | ((unsigned int)o[3] << 16);
    *reinterpret_cast<uint2*>(out + flat) = pack;
}

// ---------------------------------------------------------------------------
// Fused dual-pass BT-GEMM + butterfly epilogue.
//   pass0: accE[i][j] = sum_{k<2048}    P[i][k]      Q[j][k]
//   pass1: accO[i][j] = sum_{k<2048}    P[i][2048+k] Q[j][2048+k]
// EPI=1 (stage1, OutT=ushort): C[i][pi(j)] = E+O ; C[4095-i][pi(j)] = O-E
// EPI=2 (stage2, OutT=float) : C[i][j]     = E+O ; C[i][4095-j]     = E-O
// Tile BM=BMU*64 x BN=BNU*64 (BMU+BNU=6), 8 waves of 64x64, BK=64.
// LDS: 3-deep x (6 units x 64rows x 64k) = 144 KiB. One barrier/K-tile;
// stage t+2 during t; vmcnt(6) at tile end (t+1 landed, t+2 in flight).
// ---------------------------------------------------------------------------
#define BARRIER __builtin_amdgcn_s_barrier()
#define LGKM0 asm volatile("s_waitcnt lgkmcnt(0)" ::: "memory")
#define VM6 asm volatile("s_waitcnt vmcnt(6)" ::: "memory")
#define VM0 asm volatile("s_waitcnt vmcnt(0)" ::: "memory")
#define PRIO1 __builtin_amdgcn_s_setprio(1)
#define PRIO0 __builtin_amdgcn_s_setprio(0)

#define STAGE_ALL(LB, KC) do { \
    _Pragma("unroll") for (int U = 0; U < BMU; ++U) \
        async16(pA + (size_t)U * 64 * 4096 + (KC), &lds[(LB) + U * 4096 + ldst]); \
    _Pragma("unroll") for (int U = 0; U < BNU; ++U) \
        async16(pB + (size_t)U * 64 * 4096 + (KC), &lds[(LB) + (BMU + U) * 4096 + ldst]); } while (0)

#define LD_ALL(LB) do { \
    _Pragma("unroll") for (int mm = 0; mm < 4; ++mm) { \
        af[mm][0] = *(const bf16x8*)&lds[(LB) + aOff + mm * 1024 + sl0]; \
        af[mm][1] = *(const bf16x8*)&lds[(LB) + aOff + mm * 1024 + sl1]; } \
    _Pragma("unroll") for (int nn = 0; nn < 4; ++nn) { \
        bfr[nn][0] = *(const bf16x8*)&lds[(LB) + bOff + nn * 1024 + sl0]; \
        bfr[nn][1] = *(const bf16x8*)&lds[(LB) + bOff + nn * 1024 + sl1]; } } while (0)

#define MFMA_ALL(ACC) do { \
    _Pragma("unroll") for (int ks = 0; ks < 2; ++ks) \
    _Pragma("unroll") for (int mm = 0; mm < 4; ++mm) \
    _Pragma("unroll") for (int nn = 0; nn < 4; ++nn) \
        ACC[mm][nn] = __builtin_amdgcn_mfma_f32_16x16x32_bf16( \
            af[mm][ks], bfr[nn][ks], ACC[mm][nn], 0, 0, 0); } while (0)

template <int BMU, int BNU, int EPI, typename OutT>
__global__ __launch_bounds__(512, 2) void gemm_fused(
    const unsigned short* __restrict__ P,
    const unsigned short* __restrict__ Q,
    OutT* __restrict__ C)
{
    __shared__ __align__(16) unsigned short lds[3 * 6 * 4096];

    const int tid  = threadIdx.x;
    const int lane = tid & 63;
    const int w    = tid >> 6;
    const int wm   = w / BNU;
    const int wn   = w % BNU;

    // XCD-bijective swizzle over 256 blocks; 16x16 tile grid
    const int bid = blockIdx.x;
    const int wg  = (bid & 7) * 32 + (bid >> 3);
    const int brow = (wg >> 4) * (BMU * 64);
    const int bcol = (wg & 15) * (BNU * 64);

    // staging: thread -> (64-row unit row, 16B slot), source col pre-swizzled
    const int srow = tid >> 3;
    const int sxor = ((tid & 7) ^ (srow & 7)) << 3;
    const unsigned short* pA = P + (size_t)(brow + srow) * 4096 + sxor;
    const unsigned short* pB = Q + (size_t)(bcol + srow) * 4096 + sxor;
    const int ldst = w << 9;     // wave-uniform LDS dest (+lane*16B by HW)

    // fragment-read constants (read-side swizzle matches source XOR)
    const int lr = lane & 15, lk = lane >> 4, sx = lr & 7;
    const int sl0 = ((lk) ^ sx) << 3;
    const int sl1 = ((4 + lk) ^ sx) << 3;
    const int aOff = (wm * 64 + lr) * 64;
    const int bOff = BMU * 4096 + (wn * 64 + lr) * 64;

    bf16x8 af[4][2], bfr[4][2];
    f32x4 accE[4][4] = {};
    f32x4 accO[4][4] = {};

    // prologue: tiles 0,1 -> buffers 0,1
    STAGE_ALL(0, 0);
    STAGE_ALL(24576, 64);
    VM6;
    BARRIER;

    int b = 0;                              // current buffer index 0..2
    // pass 0 (E): tiles 0..31
    for (int t = 0; t < 32; ++t) {
        const int lb = b * 24576;
        const int bs = (b >= 1 ? b - 1 : b + 2) * 24576;   // (b+2)%3
        LD_ALL(lb);
        const int tt = t + 2;
        const int kc = ((tt >> 5) << 11) + ((tt & 31) << 6);
        STAGE_ALL(bs, kc);
        PRIO1; MFMA_ALL(accE); PRIO0;
        LGKM0; VM6; BARRIER;
        b = (b == 2) ? 0 : b + 1;
    }
    // pass 1 (O): tiles 32..61
    for (int t = 32; t < 62; ++t) {
        const int lb = b * 24576;
        const int bs = (b >= 1 ? b - 1 : b + 2) * 24576;
        LD_ALL(lb);
        const int tt = t + 2;
        const int kc = ((tt >> 5) << 11) + ((tt & 31) << 6);
        STAGE_ALL(bs, kc);
        PRIO1; MFMA_ALL(accO); PRIO0;
        LGKM0; VM6; BARRIER;
        b = (b == 2) ? 0 : b + 1;
    }
    // tile 62: no stage, drain
    {
        const int lb = b * 24576;
        LD_ALL(lb);
        PRIO1; MFMA_ALL(accO); PRIO0;
        LGKM0; VM0; BARRIER;
        b = (b == 2) ? 0 : b + 1;
    }
    // tile 63: no stage, no barrier
    {
        const int lb = b * 24576;
        LD_ALL(lb);
        PRIO1; MFMA_ALL(accO); PRIO0;
    }

    // fused butterfly epilogue. frag: row=(lane>>4)*4+r, col=lane&15
    const int r0 = brow + wm * 64 + (lane >> 4) * 4;
    const int c0 = bcol + wn * 64 + (lane & 15);
#pragma unroll
    for (int mf = 0; mf < 4; ++mf)
#pragma unroll
        for (int nf = 0; nf < 4; ++nf)
#pragma unroll
            for (int r = 0; r < 4; ++r) {
                const int row = r0 + mf * 16 + r;
                const int col = c0 + nf * 16;
                const float e = accE[mf][nf][r];
                const float o = accO[mf][nf][r];
                if (EPI == 1) {
                    // T[u][pi(n)] = E+O ; T[4095-u][pi(n)] = O-E   (bf16)
                    const int pin = (col >> 1) + ((col & 1) << 11);
                    ((unsigned short*)C)[(size_t)row * 4096 + pin] = f2bf(e + o);
                    ((unsigned short*)C)[(size_t)(4095 - row) * 4096 + pin] = f2bf(o - e);
                } else {
                    // out[u][v] = E+O ; out[u][4095-v] = E-O        (f32)
                    ((float*)C)[(size_t)row * 4096 + col] = e + o;
                    ((float*)C)[(size_t)row * 4096 + 4095 - col] = e - o;
                }
            }
}

// ---------------------------------------------------------------------------
// launch:
//   Xt = X^T (bf16, even/odd m packed)          -> R0
//   W1 = [sin_e | sin_o]                        -> R1
//   T  = fused(IDXST stage + butterfly)          -> R2   (pi-packed n cols)
//   W2 = [cos_e | cos_o]                        -> R1
//   out = fused(IDCT stage + butterfly)          -> d_out (f32)
// ws: R0 32MB | R1 16MB | R2 32MB = 80MB
// ---------------------------------------------------------------------------
extern "C" void kernel_launch(void* const* d_in, const int* in_sizes, int n_in,
                              void* d_out, int out_size, void* d_ws, size_t ws_size,
                              hipStream_t stream) {
    const float* X = (const float*)d_in[0];
    const int Mr = in_sizes[1] / 2;   // 4096
    const int Nc = in_sizes[2] / 2;   // 4096

    unsigned short* R0 = (unsigned short*)d_ws;          // Xt [4096][4096]
    unsigned short* R1 = R0 + (size_t)Mr * Nc;           // W  [2048][4096]
    unsigned short* R2 = R1 + (size_t)(Mr / 2) * Nc;     // T  [4096][4096]

    transpose_perm<<<dim3(Nc / 64, Mr / 64), 256, 0, stream>>>(X, R0, Mr, Nc);
    gen_w<<<(2048 * 4096 / 4) / 256, 256, 0, stream>>>(R1, 1);
    gemm_fused<2, 4, 1, unsigned short><<<256, 512, 0, stream>>>(R1, R0, R2);
    gen_w<<<(2048 * 4096 / 4) / 256, 256, 0, stream>>>(R1, 0);
    gemm_fused<4, 2, 2, float><<<256, 512, 0, stream>>>(R2, R1, (float*)d_out);
}